// Round 10
// baseline (243.894 us; speedup 1.0000x reference)
//
#include <hip/hip_runtime.h>

#define NN 50000
#define D 128
#define EPS 1e-8f
#define NSCAN 50176          // 49 * 1024 >= NN
#define NB_SCAN 49
#define NODES_PER_BLOCK 16

__device__ __forceinline__ unsigned short f2b(float f) {
    unsigned int u = __float_as_uint(f);
    u += 0x7FFFu + ((u >> 16) & 1u);      // round-to-nearest-even
    return (unsigned short)(u >> 16);
}
__device__ __forceinline__ float b2f(unsigned short s) {
    return __uint_as_float(((unsigned int)s) << 16);
}

// ---------------- prep: dst histogram + x->bf16 + WT build (fused) ----------------
__global__ __launch_bounds__(256) void prep_kernel(
        const int* __restrict__ dst, int* __restrict__ count,
        const float* __restrict__ x, ushort* __restrict__ xb,
        const float* __restrict__ Ws, const float* __restrict__ Wn,
        float* __restrict__ WT, int E) {
    int i = blockIdx.x * 256 + threadIdx.x;
    if (i < E) atomicAdd(&count[dst[i]], 1);
    if (i < NN * D / 4) {
        float4 v = ((const float4*)x)[i];
        ushort4 o;
        o.x = f2b(v.x); o.y = f2b(v.y); o.z = f2b(v.z); o.w = f2b(v.w);
        ((ushort4*)xb)[i] = o;
    }
    if (i < 256 * 128) {
        int k = i >> 7;
        int j = i & 127;
        float v = (k < 128) ? Ws[j * 128 + k] : Wn[j * 128 + (k - 128)];
        WT[i] = v;
    }
}

// ---------------- scan step 1: pad counts to even, per-block exclusive scan ----------------
__global__ __launch_bounds__(1024) void scan1_kernel(const int* __restrict__ count,
                                                     int* __restrict__ offsets,
                                                     int* __restrict__ bsum) {
    __shared__ int tmp[1024];
    int t = threadIdx.x;
    int gid = blockIdx.x * 1024 + t;
    int c = (count[gid] + 1) & ~1;        // pad each node to even edge count
    tmp[t] = c;
    __syncthreads();
    for (int off = 1; off < 1024; off <<= 1) {
        int v = (t >= off) ? tmp[t - off] : 0;
        __syncthreads();
        tmp[t] += v;
        __syncthreads();
    }
    offsets[gid] = tmp[t] - c;
    if (t == 1023) bsum[blockIdx.x] = tmp[t];
}

// ---------------- scan step 2+3: scan block sums (redundant per block) + add + cursor ----------------
__global__ __launch_bounds__(1024) void scan23_kernel(int* __restrict__ offsets,
                                                      const int* __restrict__ bsum,
                                                      int* __restrict__ cursor) {
    __shared__ int bs[64];
    int t = threadIdx.x;
    if (t < 64) {
        int orig = (t < NB_SCAN) ? bsum[t] : 0;
        int v = orig;
        #pragma unroll
        for (int off = 1; off < 64; off <<= 1) {
            int u = __shfl_up(v, off);
            if (t >= off) v += u;
        }
        bs[t] = v - orig;    // exclusive
    }
    __syncthreads();
    int gid = blockIdx.x * 1024 + t;
    int val = offsets[gid] + bs[blockIdx.x];
    offsets[gid] = val;
    cursor[gid] = val;
}

// ---------------- permute edges into CSR order (pad slots stay zeroed) ----------------
__global__ __launch_bounds__(256) void csr_scatter_kernel(
        const int* __restrict__ src, const int* __restrict__ dst,
        const float* __restrict__ ew, int* __restrict__ cursor,
        int2* __restrict__ edge_sw, int E) {
    int e = blockIdx.x * 256 + threadIdx.x;
    if (e >= E) return;
    int d = dst[e];
    int pos = atomicAdd(&cursor[d], 1);
    edge_sw[pos] = make_int2(src[e], __float_as_int(ew[e]));
}

// ---------------- fused gather(bf16, 8-edge chunks) + dual GEMM + bias ----------------
// 16 nodes/block, 3125 blocks -> ~12 blocks/CU available, occupancy to the 32-wave cap.
__global__ __launch_bounds__(256) void fused_out_kernel(
        const float* __restrict__ x, const ushort* __restrict__ xb,
        const int* __restrict__ offsets, const int2* __restrict__ edge_sw,
        const float* __restrict__ WT, const float* __restrict__ b_self,
        const float* __restrict__ bias, float* __restrict__ out) {
    __shared__ float HN[NODES_PER_BLOCK][128];
    int tid = threadIdx.x;
    int v0 = blockIdx.x * NODES_PER_BLOCK;
    int lane = tid & 63;
    int wid = tid >> 6;
    int half = lane >> 5;
    int l32 = lane & 31;

    // gather h_neigh: wave wid owns nodes wid*4..wid*4+3; counts are even (padded, w=0 pads)
    for (int q = 0; q < 4; ++q) {
        int nn = wid * 4 + q;
        int v = v0 + nn;
        float4 acc = make_float4(0.f, 0.f, 0.f, 0.f);
        float wsum = 0.f;
        {
            int beg = offsets[v];
            int end = offsets[v + 1];
            int cnt = end - beg;               // even
            int i = beg;
            int n8 = cnt & ~7;
            for (; i < beg + n8; i += 8) {
                // half h handles edges i+4h .. i+4h+3 (16B-aligned int4 metas)
                int4 mA = *(const int4*)(edge_sw + i + 4 * half);
                int4 mB = *(const int4*)(edge_sw + i + 4 * half + 2);
                float w0 = __int_as_float(mA.y), w1 = __int_as_float(mA.w);
                float w2 = __int_as_float(mB.y), w3 = __int_as_float(mB.w);
                ushort4 r0 = *((const ushort4*)(xb + (size_t)mA.x * D) + l32);
                ushort4 r1 = *((const ushort4*)(xb + (size_t)mA.z * D) + l32);
                ushort4 r2 = *((const ushort4*)(xb + (size_t)mB.x * D) + l32);
                ushort4 r3 = *((const ushort4*)(xb + (size_t)mB.z * D) + l32);
                acc.x = fmaf(b2f(r0.x), w0, acc.x); acc.y = fmaf(b2f(r0.y), w0, acc.y);
                acc.z = fmaf(b2f(r0.z), w0, acc.z); acc.w = fmaf(b2f(r0.w), w0, acc.w);
                acc.x = fmaf(b2f(r1.x), w1, acc.x); acc.y = fmaf(b2f(r1.y), w1, acc.y);
                acc.z = fmaf(b2f(r1.z), w1, acc.z); acc.w = fmaf(b2f(r1.w), w1, acc.w);
                acc.x = fmaf(b2f(r2.x), w2, acc.x); acc.y = fmaf(b2f(r2.y), w2, acc.y);
                acc.z = fmaf(b2f(r2.z), w2, acc.z); acc.w = fmaf(b2f(r2.w), w2, acc.w);
                acc.x = fmaf(b2f(r3.x), w3, acc.x); acc.y = fmaf(b2f(r3.y), w3, acc.y);
                acc.z = fmaf(b2f(r3.z), w3, acc.z); acc.w = fmaf(b2f(r3.w), w3, acc.w);
                wsum += (w0 + w1) + (w2 + w3);
            }
            if (cnt & 4) {
                // half h handles edges i+2h, i+2h+1
                int4 mA = *(const int4*)(edge_sw + i + 2 * half);
                float w0 = __int_as_float(mA.y), w1 = __int_as_float(mA.w);
                ushort4 r0 = *((const ushort4*)(xb + (size_t)mA.x * D) + l32);
                ushort4 r1 = *((const ushort4*)(xb + (size_t)mA.z * D) + l32);
                acc.x = fmaf(b2f(r0.x), w0, acc.x); acc.y = fmaf(b2f(r0.y), w0, acc.y);
                acc.z = fmaf(b2f(r0.z), w0, acc.z); acc.w = fmaf(b2f(r0.w), w0, acc.w);
                acc.x = fmaf(b2f(r1.x), w1, acc.x); acc.y = fmaf(b2f(r1.y), w1, acc.y);
                acc.z = fmaf(b2f(r1.z), w1, acc.z); acc.w = fmaf(b2f(r1.w), w1, acc.w);
                wsum += w0 + w1;
                i += 4;
            }
            if ((cnt & 2) && half == 0) {
                // last 2 edges (may include the zero pad)
                int4 mA = *(const int4*)(edge_sw + i);
                float w0 = __int_as_float(mA.y), w1 = __int_as_float(mA.w);
                ushort4 r0 = *((const ushort4*)(xb + (size_t)mA.x * D) + l32);
                ushort4 r1 = *((const ushort4*)(xb + (size_t)mA.z * D) + l32);
                acc.x = fmaf(b2f(r0.x), w0, acc.x); acc.y = fmaf(b2f(r0.y), w0, acc.y);
                acc.z = fmaf(b2f(r0.z), w0, acc.z); acc.w = fmaf(b2f(r0.w), w0, acc.w);
                acc.x = fmaf(b2f(r1.x), w1, acc.x); acc.y = fmaf(b2f(r1.y), w1, acc.y);
                acc.z = fmaf(b2f(r1.z), w1, acc.z); acc.w = fmaf(b2f(r1.w), w1, acc.w);
                wsum += w0 + w1;
            }
        }
        acc.x += __shfl_xor(acc.x, 32);
        acc.y += __shfl_xor(acc.y, 32);
        acc.z += __shfl_xor(acc.z, 32);
        acc.w += __shfl_xor(acc.w, 32);
        wsum  += __shfl_xor(wsum, 32);
        if (half == 0) {
            float inv = 1.0f / (wsum + EPS);
            *(float4*)&HN[nn][l32 * 4] =
                make_float4(acc.x * inv, acc.y * inv, acc.z * inv, acc.w * inv);
        }
    }
    __syncthreads();

    // GEMM: out[v][j] = sum_k x[v][k]*WT[k][j] + sum_k hn[v][k]*WT[128+k][j] + biases
    // 2048 outputs / 256 threads = 2 nodes x 4 cols per thread.
    int j0 = (tid & 31) * 4;
    int ns = tid >> 5;               // 0..7 -> nodes ns*2, ns*2+1
    float acc[2][4];
    #pragma unroll
    for (int n = 0; n < 2; ++n)
        #pragma unroll
        for (int j = 0; j < 4; ++j) acc[n][j] = 0.f;

    int row0 = v0 + ns * 2;

    // self half: A from global x (per-wave broadcast, L1/L2-resident)
    for (int k4 = 0; k4 < 128; k4 += 4) {
        float4 w0 = *(const float4*)(WT + (k4 + 0) * D + j0);
        float4 w1 = *(const float4*)(WT + (k4 + 1) * D + j0);
        float4 w2 = *(const float4*)(WT + (k4 + 2) * D + j0);
        float4 w3 = *(const float4*)(WT + (k4 + 3) * D + j0);
        #pragma unroll
        for (int n = 0; n < 2; ++n) {
            float4 a = *(const float4*)(x + (size_t)(row0 + n) * D + k4);
            acc[n][0] = fmaf(a.x, w0.x, fmaf(a.y, w1.x, fmaf(a.z, w2.x, fmaf(a.w, w3.x, acc[n][0]))));
            acc[n][1] = fmaf(a.x, w0.y, fmaf(a.y, w1.y, fmaf(a.z, w2.y, fmaf(a.w, w3.y, acc[n][1]))));
            acc[n][2] = fmaf(a.x, w0.z, fmaf(a.y, w1.z, fmaf(a.z, w2.z, fmaf(a.w, w3.z, acc[n][2]))));
            acc[n][3] = fmaf(a.x, w0.w, fmaf(a.y, w1.w, fmaf(a.z, w2.w, fmaf(a.w, w3.w, acc[n][3]))));
        }
    }
    // neigh half: A from LDS HN
    for (int k4 = 0; k4 < 128; k4 += 4) {
        float4 w0 = *(const float4*)(WT + (128 + k4 + 0) * D + j0);
        float4 w1 = *(const float4*)(WT + (128 + k4 + 1) * D + j0);
        float4 w2 = *(const float4*)(WT + (128 + k4 + 2) * D + j0);
        float4 w3 = *(const float4*)(WT + (128 + k4 + 3) * D + j0);
        #pragma unroll
        for (int n = 0; n < 2; ++n) {
            float4 a = *(const float4*)&HN[ns * 2 + n][k4];
            acc[n][0] = fmaf(a.x, w0.x, fmaf(a.y, w1.x, fmaf(a.z, w2.x, fmaf(a.w, w3.x, acc[n][0]))));
            acc[n][1] = fmaf(a.x, w0.y, fmaf(a.y, w1.y, fmaf(a.z, w2.y, fmaf(a.w, w3.y, acc[n][1]))));
            acc[n][2] = fmaf(a.x, w0.z, fmaf(a.y, w1.z, fmaf(a.z, w2.z, fmaf(a.w, w3.z, acc[n][2]))));
            acc[n][3] = fmaf(a.x, w0.w, fmaf(a.y, w1.w, fmaf(a.z, w2.w, fmaf(a.w, w3.w, acc[n][3]))));
        }
    }

    float4 b  = *(const float4*)(b_self + j0);
    float4 bp = *(const float4*)(bias + j0);
    b.x += bp.x; b.y += bp.y; b.z += bp.z; b.w += bp.w;

    #pragma unroll
    for (int n = 0; n < 2; ++n) {
        int v = row0 + n;
        float4 o;
        o.x = acc[n][0] + b.x;
        o.y = acc[n][1] + b.y;
        o.z = acc[n][2] + b.z;
        o.w = acc[n][3] + b.w;
        *(float4*)(out + (size_t)v * D + j0) = o;
    }
}

extern "C" void kernel_launch(void* const* d_in, const int* in_sizes, int n_in,
                              void* d_out, int out_size, void* d_ws, size_t ws_size,
                              hipStream_t stream) {
    const float* x   = (const float*)d_in[0];
    const int*   src = (const int*)d_in[1];
    const int*   dst = (const int*)d_in[2];
    const float* ew  = (const float*)d_in[3];
    const float* Ws  = (const float*)d_in[4];
    const float* bs  = (const float*)d_in[5];
    const float* Wn  = (const float*)d_in[6];
    const float* bp  = (const float*)d_in[7];
    float* out = (float*)d_out;

    int E = in_sizes[1];
    int EPAD = E + NSCAN;                       // room for 1 pad edge per node

    // workspace layout (4B units): count and edge_sw contiguous for single memset
    int*  wsi     = (int*)d_ws;
    int*  count   = wsi;                        // NSCAN
    int2* edge_sw = (int2*)(wsi + NSCAN);       // EPAD int2 (16B-aligned: NSCAN*4 % 16 == 0)
    int*  offsets = wsi + NSCAN + 2 * EPAD;     // NSCAN
    int*  cursor  = offsets + NSCAN;            // NSCAN
    int*  bsum    = cursor + NSCAN;             // 64
    float* WT     = (float*)(bsum + 64);        // 256*128 floats
    ushort* xb    = (ushort*)(WT + 256 * 128);  // NN*D bf16

    // zero count + edge_sw (pads must read as src=0, w=0)
    hipMemsetAsync(count, 0, (size_t)(NSCAN + 2 * EPAD) * sizeof(int), stream);

    int ncvt = NN * D / 4;
    int nmax = (E > ncvt) ? E : ncvt;
    prep_kernel<<<(nmax + 255) / 256, 256, 0, stream>>>(dst, count, x, xb, Ws, Wn, WT, E);

    scan1_kernel<<<NB_SCAN, 1024, 0, stream>>>(count, offsets, bsum);
    scan23_kernel<<<NB_SCAN, 1024, 0, stream>>>(offsets, bsum, cursor);
    csr_scatter_kernel<<<(E + 255) / 256, 256, 0, stream>>>(src, dst, ew, cursor, edge_sw, E);

    fused_out_kernel<<<NN / NODES_PER_BLOCK, 256, 0, stream>>>(x, xb, offsets, edge_sw,
                                                               WT, bs, bp, out);
}

// Round 11
// 225.034 us; speedup vs baseline: 1.0838x; 1.0838x over previous
//
#include <hip/hip_runtime.h>

#define NN 50000
#define D 128
#define EPS 1e-8f
#define NSCAN 50176          // 49 * 1024 >= NN
#define NB_SCAN 49
#define NODES_PER_BLOCK 24

__device__ __forceinline__ unsigned short f2b(float f) {
    unsigned int u = __float_as_uint(f);
    u += 0x7FFFu + ((u >> 16) & 1u);      // round-to-nearest-even
    return (unsigned short)(u >> 16);
}
__device__ __forceinline__ float b2f(unsigned short s) {
    return __uint_as_float(((unsigned int)s) << 16);
}

// ---------------- prep: dst histogram + x->bf16 + WT build (fused) ----------------
__global__ __launch_bounds__(256) void prep_kernel(
        const int* __restrict__ dst, int* __restrict__ count,
        const float* __restrict__ x, ushort* __restrict__ xb,
        const float* __restrict__ Ws, const float* __restrict__ Wn,
        float* __restrict__ WT, int E) {
    int i = blockIdx.x * 256 + threadIdx.x;
    if (i < E) atomicAdd(&count[dst[i]], 1);
    if (i < NN * D / 4) {
        float4 v = ((const float4*)x)[i];
        ushort4 o;
        o.x = f2b(v.x); o.y = f2b(v.y); o.z = f2b(v.z); o.w = f2b(v.w);
        ((ushort4*)xb)[i] = o;
    }
    if (i < 256 * 128) {
        int k = i >> 7;
        int j = i & 127;
        float v = (k < 128) ? Ws[j * 128 + k] : Wn[j * 128 + (k - 128)];
        WT[i] = v;
    }
}

// ---------------- scan step 1: pad counts to even, per-block exclusive scan ----------------
__global__ __launch_bounds__(1024) void scan1_kernel(const int* __restrict__ count,
                                                     int* __restrict__ offsets,
                                                     int* __restrict__ bsum) {
    __shared__ int tmp[1024];
    int t = threadIdx.x;
    int gid = blockIdx.x * 1024 + t;
    int c = (count[gid] + 1) & ~1;        // pad each node to even edge count
    tmp[t] = c;
    __syncthreads();
    for (int off = 1; off < 1024; off <<= 1) {
        int v = (t >= off) ? tmp[t - off] : 0;
        __syncthreads();
        tmp[t] += v;
        __syncthreads();
    }
    offsets[gid] = tmp[t] - c;
    if (t == 1023) bsum[blockIdx.x] = tmp[t];
}

// ---------------- scan step 2+3: scan block sums (redundant per block) + add + cursor ----------------
__global__ __launch_bounds__(1024) void scan23_kernel(int* __restrict__ offsets,
                                                      const int* __restrict__ bsum,
                                                      int* __restrict__ cursor) {
    __shared__ int bs[64];
    int t = threadIdx.x;
    if (t < 64) {
        int orig = (t < NB_SCAN) ? bsum[t] : 0;
        int v = orig;
        #pragma unroll
        for (int off = 1; off < 64; off <<= 1) {
            int u = __shfl_up(v, off);
            if (t >= off) v += u;
        }
        bs[t] = v - orig;    // exclusive
    }
    __syncthreads();
    int gid = blockIdx.x * 1024 + t;
    int val = offsets[gid] + bs[blockIdx.x];
    offsets[gid] = val;
    cursor[gid] = val;
}

// ---------------- permute edges into CSR order (pad slots stay zeroed) ----------------
__global__ __launch_bounds__(256) void csr_scatter_kernel(
        const int* __restrict__ src, const int* __restrict__ dst,
        const float* __restrict__ ew, int* __restrict__ cursor,
        int2* __restrict__ edge_sw, int E) {
    int e = blockIdx.x * 256 + threadIdx.x;
    if (e >= E) return;
    int d = dst[e];
    int pos = atomicAdd(&cursor[d], 1);
    edge_sw[pos] = make_int2(src[e], __float_as_int(ew[e]));
}

// ---------------- fused gather(bf16, 8-edge chunks, meta-prefetch) + dual GEMM + bias ----------------
// 24 nodes/block, 2084 blocks -> 8.1 blocks/CU, saturates the 8-block/32-wave cap.
__global__ __launch_bounds__(256) void fused_out_kernel(
        const float* __restrict__ x, const ushort* __restrict__ xb,
        const int* __restrict__ offsets, const int2* __restrict__ edge_sw,
        const float* __restrict__ WT, const float* __restrict__ b_self,
        const float* __restrict__ bias, float* __restrict__ out) {
    __shared__ float HN[NODES_PER_BLOCK][128];
    int tid = threadIdx.x;
    int v0 = blockIdx.x * NODES_PER_BLOCK;
    int lane = tid & 63;
    int wid = tid >> 6;
    int half = lane >> 5;
    int l32 = lane & 31;

    // gather h_neigh: wave wid owns nodes wid*6..wid*6+5; counts are even (padded, w=0 pads)
    for (int q = 0; q < 6; ++q) {
        int nn = wid * 6 + q;
        int v = v0 + nn;
        float4 acc = make_float4(0.f, 0.f, 0.f, 0.f);
        float wsum = 0.f;
        if (v < NN) {
            int beg = offsets[v];
            int end = offsets[v + 1];
            int cnt = end - beg;               // even
            int i = beg;
            int n8 = cnt & ~7;
            int end8 = beg + n8;
            if (n8) {
                // prefetch first chunk's metas (this half's 4 edges)
                int4 mA = *(const int4*)(edge_sw + i + 4 * half);
                int4 mB = *(const int4*)(edge_sw + i + 4 * half + 2);
                while (i < end8) {
                    i += 8;
                    int4 nA, nB;
                    if (i < end8) {           // issue NEXT metas before current rows
                        nA = *(const int4*)(edge_sw + i + 4 * half);
                        nB = *(const int4*)(edge_sw + i + 4 * half + 2);
                    }
                    float w0 = __int_as_float(mA.y), w1 = __int_as_float(mA.w);
                    float w2 = __int_as_float(mB.y), w3 = __int_as_float(mB.w);
                    ushort4 r0 = *((const ushort4*)(xb + (size_t)mA.x * D) + l32);
                    ushort4 r1 = *((const ushort4*)(xb + (size_t)mA.z * D) + l32);
                    ushort4 r2 = *((const ushort4*)(xb + (size_t)mB.x * D) + l32);
                    ushort4 r3 = *((const ushort4*)(xb + (size_t)mB.z * D) + l32);
                    acc.x = fmaf(b2f(r0.x), w0, acc.x); acc.y = fmaf(b2f(r0.y), w0, acc.y);
                    acc.z = fmaf(b2f(r0.z), w0, acc.z); acc.w = fmaf(b2f(r0.w), w0, acc.w);
                    acc.x = fmaf(b2f(r1.x), w1, acc.x); acc.y = fmaf(b2f(r1.y), w1, acc.y);
                    acc.z = fmaf(b2f(r1.z), w1, acc.z); acc.w = fmaf(b2f(r1.w), w1, acc.w);
                    acc.x = fmaf(b2f(r2.x), w2, acc.x); acc.y = fmaf(b2f(r2.y), w2, acc.y);
                    acc.z = fmaf(b2f(r2.z), w2, acc.z); acc.w = fmaf(b2f(r2.w), w2, acc.w);
                    acc.x = fmaf(b2f(r3.x), w3, acc.x); acc.y = fmaf(b2f(r3.y), w3, acc.y);
                    acc.z = fmaf(b2f(r3.z), w3, acc.z); acc.w = fmaf(b2f(r3.w), w3, acc.w);
                    wsum += (w0 + w1) + (w2 + w3);
                    mA = nA; mB = nB;
                }
            }
            if (cnt & 4) {
                int4 mA = *(const int4*)(edge_sw + i + 2 * half);
                float w0 = __int_as_float(mA.y), w1 = __int_as_float(mA.w);
                ushort4 r0 = *((const ushort4*)(xb + (size_t)mA.x * D) + l32);
                ushort4 r1 = *((const ushort4*)(xb + (size_t)mA.z * D) + l32);
                acc.x = fmaf(b2f(r0.x), w0, acc.x); acc.y = fmaf(b2f(r0.y), w0, acc.y);
                acc.z = fmaf(b2f(r0.z), w0, acc.z); acc.w = fmaf(b2f(r0.w), w0, acc.w);
                acc.x = fmaf(b2f(r1.x), w1, acc.x); acc.y = fmaf(b2f(r1.y), w1, acc.y);
                acc.z = fmaf(b2f(r1.z), w1, acc.z); acc.w = fmaf(b2f(r1.w), w1, acc.w);
                wsum += w0 + w1;
                i += 4;
            }
            if ((cnt & 2) && half == 0) {
                int4 mA = *(const int4*)(edge_sw + i);
                float w0 = __int_as_float(mA.y), w1 = __int_as_float(mA.w);
                ushort4 r0 = *((const ushort4*)(xb + (size_t)mA.x * D) + l32);
                ushort4 r1 = *((const ushort4*)(xb + (size_t)mA.z * D) + l32);
                acc.x = fmaf(b2f(r0.x), w0, acc.x); acc.y = fmaf(b2f(r0.y), w0, acc.y);
                acc.z = fmaf(b2f(r0.z), w0, acc.z); acc.w = fmaf(b2f(r0.w), w0, acc.w);
                acc.x = fmaf(b2f(r1.x), w1, acc.x); acc.y = fmaf(b2f(r1.y), w1, acc.y);
                acc.z = fmaf(b2f(r1.z), w1, acc.z); acc.w = fmaf(b2f(r1.w), w1, acc.w);
                wsum += w0 + w1;
            }
        }
        acc.x += __shfl_xor(acc.x, 32);
        acc.y += __shfl_xor(acc.y, 32);
        acc.z += __shfl_xor(acc.z, 32);
        acc.w += __shfl_xor(acc.w, 32);
        wsum  += __shfl_xor(wsum, 32);
        if (half == 0 && v < NN) {
            float inv = 1.0f / (wsum + EPS);
            *(float4*)&HN[nn][l32 * 4] =
                make_float4(acc.x * inv, acc.y * inv, acc.z * inv, acc.w * inv);
        }
    }
    __syncthreads();

    // GEMM: out[v][j] = sum_k x[v][k]*WT[k][j] + sum_k hn[v][k]*WT[128+k][j] + biases
    // 24*128 = 3072 outputs / 256 threads = 3 nodes x 4 cols per thread.
    int j0 = (tid & 31) * 4;
    int ns = tid >> 5;               // 0..7 -> nodes ns*3 .. ns*3+2
    float acc[3][4];
    #pragma unroll
    for (int n = 0; n < 3; ++n)
        #pragma unroll
        for (int j = 0; j < 4; ++j) acc[n][j] = 0.f;

    int rowc[3];
    #pragma unroll
    for (int n = 0; n < 3; ++n) {
        int rv = v0 + ns * 3 + n;
        rowc[n] = (rv < NN) ? rv : (NN - 1);   // clamped read; store is guarded
    }

    // self half: A from global x (per-wave broadcast, L1/L2-resident)
    for (int k4 = 0; k4 < 128; k4 += 4) {
        float4 w0 = *(const float4*)(WT + (k4 + 0) * D + j0);
        float4 w1 = *(const float4*)(WT + (k4 + 1) * D + j0);
        float4 w2 = *(const float4*)(WT + (k4 + 2) * D + j0);
        float4 w3 = *(const float4*)(WT + (k4 + 3) * D + j0);
        #pragma unroll
        for (int n = 0; n < 3; ++n) {
            float4 a = *(const float4*)(x + (size_t)rowc[n] * D + k4);
            acc[n][0] = fmaf(a.x, w0.x, fmaf(a.y, w1.x, fmaf(a.z, w2.x, fmaf(a.w, w3.x, acc[n][0]))));
            acc[n][1] = fmaf(a.x, w0.y, fmaf(a.y, w1.y, fmaf(a.z, w2.y, fmaf(a.w, w3.y, acc[n][1]))));
            acc[n][2] = fmaf(a.x, w0.z, fmaf(a.y, w1.z, fmaf(a.z, w2.z, fmaf(a.w, w3.z, acc[n][2]))));
            acc[n][3] = fmaf(a.x, w0.w, fmaf(a.y, w1.w, fmaf(a.z, w2.w, fmaf(a.w, w3.w, acc[n][3]))));
        }
    }
    // neigh half: A from LDS HN
    for (int k4 = 0; k4 < 128; k4 += 4) {
        float4 w0 = *(const float4*)(WT + (128 + k4 + 0) * D + j0);
        float4 w1 = *(const float4*)(WT + (128 + k4 + 1) * D + j0);
        float4 w2 = *(const float4*)(WT + (128 + k4 + 2) * D + j0);
        float4 w3 = *(const float4*)(WT + (128 + k4 + 3) * D + j0);
        #pragma unroll
        for (int n = 0; n < 3; ++n) {
            float4 a = *(const float4*)&HN[ns * 3 + n][k4];
            acc[n][0] = fmaf(a.x, w0.x, fmaf(a.y, w1.x, fmaf(a.z, w2.x, fmaf(a.w, w3.x, acc[n][0]))));
            acc[n][1] = fmaf(a.x, w0.y, fmaf(a.y, w1.y, fmaf(a.z, w2.y, fmaf(a.w, w3.y, acc[n][1]))));
            acc[n][2] = fmaf(a.x, w0.z, fmaf(a.y, w1.z, fmaf(a.z, w2.z, fmaf(a.w, w3.z, acc[n][2]))));
            acc[n][3] = fmaf(a.x, w0.w, fmaf(a.y, w1.w, fmaf(a.z, w2.w, fmaf(a.w, w3.w, acc[n][3]))));
        }
    }

    float4 b  = *(const float4*)(b_self + j0);
    float4 bp = *(const float4*)(bias + j0);
    b.x += bp.x; b.y += bp.y; b.z += bp.z; b.w += bp.w;

    #pragma unroll
    for (int n = 0; n < 3; ++n) {
        int v = v0 + ns * 3 + n;
        if (v < NN) {
            float4 o;
            o.x = acc[n][0] + b.x;
            o.y = acc[n][1] + b.y;
            o.z = acc[n][2] + b.z;
            o.w = acc[n][3] + b.w;
            *(float4*)(out + (size_t)v * D + j0) = o;
        }
    }
}

extern "C" void kernel_launch(void* const* d_in, const int* in_sizes, int n_in,
                              void* d_out, int out_size, void* d_ws, size_t ws_size,
                              hipStream_t stream) {
    const float* x   = (const float*)d_in[0];
    const int*   src = (const int*)d_in[1];
    const int*   dst = (const int*)d_in[2];
    const float* ew  = (const float*)d_in[3];
    const float* Ws  = (const float*)d_in[4];
    const float* bs  = (const float*)d_in[5];
    const float* Wn  = (const float*)d_in[6];
    const float* bp  = (const float*)d_in[7];
    float* out = (float*)d_out;

    int E = in_sizes[1];
    int EPAD = E + NSCAN;                       // room for 1 pad edge per node

    // workspace layout (4B units): count and edge_sw contiguous for single memset
    int*  wsi     = (int*)d_ws;
    int*  count   = wsi;                        // NSCAN
    int2* edge_sw = (int2*)(wsi + NSCAN);       // EPAD int2 (16B-aligned: NSCAN*4 % 16 == 0)
    int*  offsets = wsi + NSCAN + 2 * EPAD;     // NSCAN
    int*  cursor  = offsets + NSCAN;            // NSCAN
    int*  bsum    = cursor + NSCAN;             // 64
    float* WT     = (float*)(bsum + 64);        // 256*128 floats
    ushort* xb    = (ushort*)(WT + 256 * 128);  // NN*D bf16

    // zero count + edge_sw (pads must read as src=0, w=0)
    hipMemsetAsync(count, 0, (size_t)(NSCAN + 2 * EPAD) * sizeof(int), stream);

    int ncvt = NN * D / 4;
    int nmax = (E > ncvt) ? E : ncvt;
    prep_kernel<<<(nmax + 255) / 256, 256, 0, stream>>>(dst, count, x, xb, Ws, Wn, WT, E);

    scan1_kernel<<<NB_SCAN, 1024, 0, stream>>>(count, offsets, bsum);
    scan23_kernel<<<NB_SCAN, 1024, 0, stream>>>(offsets, bsum, cursor);
    csr_scatter_kernel<<<(E + 255) / 256, 256, 0, stream>>>(src, dst, ew, cursor, edge_sw, E);

    fused_out_kernel<<<(NN + NODES_PER_BLOCK - 1) / NODES_PER_BLOCK, 256, 0, stream>>>(
        x, xb, offsets, edge_sw, WT, bs, bp, out);
}

// Round 13
// 210.548 us; speedup vs baseline: 1.1584x; 1.0688x over previous
//
#include <hip/hip_runtime.h>

#define NN 50000
#define D 128
#define EPS 1e-8f
#define NSCAN 50176          // 49 * 1024 >= NN
#define NB_SCAN 49

__device__ __forceinline__ unsigned short f2b(float f) {
    unsigned int u = __float_as_uint(f);
    u += 0x7FFFu + ((u >> 16) & 1u);      // round-to-nearest-even
    return (unsigned short)(u >> 16);
}
__device__ __forceinline__ float b2f(unsigned short s) {
    return __uint_as_float(((unsigned int)s) << 16);
}

__device__ __forceinline__ void edge_fma4(float4& a, ushort4 r, float w) {
    a.x = fmaf(b2f(r.x), w, a.x);
    a.y = fmaf(b2f(r.y), w, a.y);
    a.z = fmaf(b2f(r.z), w, a.z);
    a.w = fmaf(b2f(r.w), w, a.w);
}

// ---------------- prep: dst histogram + x->bf16 + WT build (fused) ----------------
__global__ __launch_bounds__(256) void prep_kernel(
        const int* __restrict__ dst, int* __restrict__ count,
        const float* __restrict__ x, ushort* __restrict__ xb,
        const float* __restrict__ Ws, const float* __restrict__ Wn,
        float* __restrict__ WT, int E) {
    int i = blockIdx.x * 256 + threadIdx.x;
    if (i < E) atomicAdd(&count[dst[i]], 1);
    if (i < NN * D / 4) {
        float4 v = ((const float4*)x)[i];
        ushort4 o;
        o.x = f2b(v.x); o.y = f2b(v.y); o.z = f2b(v.z); o.w = f2b(v.w);
        ((ushort4*)xb)[i] = o;
    }
    if (i < 256 * 128) {
        int k = i >> 7;
        int j = i & 127;
        float v = (k < 128) ? Ws[j * 128 + k] : Wn[j * 128 + (k - 128)];
        WT[i] = v;
    }
}

// ---------------- scan step 1: pad counts to even, per-block exclusive scan ----------------
__global__ __launch_bounds__(1024) void scan1_kernel(const int* __restrict__ count,
                                                     int* __restrict__ offsets,
                                                     int* __restrict__ bsum) {
    __shared__ int tmp[1024];
    int t = threadIdx.x;
    int gid = blockIdx.x * 1024 + t;
    int c = (count[gid] + 1) & ~1;        // pad each node to even edge count
    tmp[t] = c;
    __syncthreads();
    for (int off = 1; off < 1024; off <<= 1) {
        int v = (t >= off) ? tmp[t - off] : 0;
        __syncthreads();
        tmp[t] += v;
        __syncthreads();
    }
    offsets[gid] = tmp[t] - c;
    if (t == 1023) bsum[blockIdx.x] = tmp[t];
}

// ---------------- scan step 2+3: scan block sums (redundant per block) + add + cursor ----------------
__global__ __launch_bounds__(1024) void scan23_kernel(int* __restrict__ offsets,
                                                      const int* __restrict__ bsum,
                                                      int* __restrict__ cursor) {
    __shared__ int bs[64];
    int t = threadIdx.x;
    if (t < 64) {
        int orig = (t < NB_SCAN) ? bsum[t] : 0;
        int v = orig;
        #pragma unroll
        for (int off = 1; off < 64; off <<= 1) {
            int u = __shfl_up(v, off);
            if (t >= off) v += u;
        }
        bs[t] = v - orig;    // exclusive
    }
    __syncthreads();
    int gid = blockIdx.x * 1024 + t;
    int val = offsets[gid] + bs[blockIdx.x];
    offsets[gid] = val;
    cursor[gid] = val;
}

// ---------------- permute edges into CSR order (pad slots stay zeroed) ----------------
__global__ __launch_bounds__(256) void csr_scatter_kernel(
        const int* __restrict__ src, const int* __restrict__ dst,
        const float* __restrict__ ew, int* __restrict__ cursor,
        int2* __restrict__ edge_sw, int E) {
    int e = blockIdx.x * 256 + threadIdx.x;
    if (e >= E) return;
    int d = dst[e];
    int pos = atomicAdd(&cursor[d], 1);
    edge_sw[pos] = make_int2(src[e], __float_as_int(ew[e]));
}

// ---------------- fused gather(bf16, 16-edge chunks) + dual GEMM + bias ----------------
// 32 nodes/block (R9 config). Deeper chunks: 8 independent row loads in flight per half.
__global__ __launch_bounds__(256) void fused_out_kernel(
        const float* __restrict__ x, const ushort* __restrict__ xb,
        const int* __restrict__ offsets, const int2* __restrict__ edge_sw,
        const float* __restrict__ WT, const float* __restrict__ b_self,
        const float* __restrict__ bias, float* __restrict__ out) {
    __shared__ float HN[32][128];
    int tid = threadIdx.x;
    int v0 = blockIdx.x * 32;
    int lane = tid & 63;
    int wid = tid >> 6;
    int half = lane >> 5;
    int l32 = lane & 31;

    // gather h_neigh: wave wid owns nodes wid*8..wid*8+7; counts are even (padded, w=0 pads)
    for (int q = 0; q < 8; ++q) {
        int nn = wid * 8 + q;
        int v = v0 + nn;
        float4 acc = make_float4(0.f, 0.f, 0.f, 0.f);
        float wsum = 0.f;
        if (v < NN) {
            int beg = offsets[v];
            int end = offsets[v + 1];
            int cnt = end - beg;               // even
            int i = beg;
            int n16 = cnt & ~15;
            for (; i < beg + n16; i += 16) {
                // half h handles edges i+8h .. i+8h+7 (4x int4 metas, 8 row loads in flight)
                const int2* ebase = edge_sw + i + 8 * half;
                int4 mA = *(const int4*)(ebase + 0);
                int4 mB = *(const int4*)(ebase + 2);
                int4 mC = *(const int4*)(ebase + 4);
                int4 mD = *(const int4*)(ebase + 6);
                float w0 = __int_as_float(mA.y), w1 = __int_as_float(mA.w);
                float w2 = __int_as_float(mB.y), w3 = __int_as_float(mB.w);
                float w4 = __int_as_float(mC.y), w5 = __int_as_float(mC.w);
                float w6 = __int_as_float(mD.y), w7 = __int_as_float(mD.w);
                ushort4 r0 = *((const ushort4*)(xb + (size_t)mA.x * D) + l32);
                ushort4 r1 = *((const ushort4*)(xb + (size_t)mA.z * D) + l32);
                ushort4 r2 = *((const ushort4*)(xb + (size_t)mB.x * D) + l32);
                ushort4 r3 = *((const ushort4*)(xb + (size_t)mB.z * D) + l32);
                ushort4 r4 = *((const ushort4*)(xb + (size_t)mC.x * D) + l32);
                ushort4 r5 = *((const ushort4*)(xb + (size_t)mC.z * D) + l32);
                ushort4 r6 = *((const ushort4*)(xb + (size_t)mD.x * D) + l32);
                ushort4 r7 = *((const ushort4*)(xb + (size_t)mD.z * D) + l32);
                edge_fma4(acc, r0, w0); edge_fma4(acc, r1, w1);
                edge_fma4(acc, r2, w2); edge_fma4(acc, r3, w3);
                edge_fma4(acc, r4, w4); edge_fma4(acc, r5, w5);
                edge_fma4(acc, r6, w6); edge_fma4(acc, r7, w7);
                wsum += ((w0 + w1) + (w2 + w3)) + ((w4 + w5) + (w6 + w7));
            }
            if (cnt & 8) {
                const int2* ebase = edge_sw + i + 4 * half;
                int4 mA = *(const int4*)(ebase + 0);
                int4 mB = *(const int4*)(ebase + 2);
                float w0 = __int_as_float(mA.y), w1 = __int_as_float(mA.w);
                float w2 = __int_as_float(mB.y), w3 = __int_as_float(mB.w);
                ushort4 r0 = *((const ushort4*)(xb + (size_t)mA.x * D) + l32);
                ushort4 r1 = *((const ushort4*)(xb + (size_t)mA.z * D) + l32);
                ushort4 r2 = *((const ushort4*)(xb + (size_t)mB.x * D) + l32);
                ushort4 r3 = *((const ushort4*)(xb + (size_t)mB.z * D) + l32);
                edge_fma4(acc, r0, w0); edge_fma4(acc, r1, w1);
                edge_fma4(acc, r2, w2); edge_fma4(acc, r3, w3);
                wsum += (w0 + w1) + (w2 + w3);
                i += 8;
            }
            if (cnt & 4) {
                int4 mA = *(const int4*)(edge_sw + i + 2 * half);
                float w0 = __int_as_float(mA.y), w1 = __int_as_float(mA.w);
                ushort4 r0 = *((const ushort4*)(xb + (size_t)mA.x * D) + l32);
                ushort4 r1 = *((const ushort4*)(xb + (size_t)mA.z * D) + l32);
                edge_fma4(acc, r0, w0); edge_fma4(acc, r1, w1);
                wsum += w0 + w1;
                i += 4;
            }
            if ((cnt & 2) && half == 0) {
                int4 mA = *(const int4*)(edge_sw + i);
                float w0 = __int_as_float(mA.y), w1 = __int_as_float(mA.w);
                ushort4 r0 = *((const ushort4*)(xb + (size_t)mA.x * D) + l32);
                ushort4 r1 = *((const ushort4*)(xb + (size_t)mA.z * D) + l32);
                edge_fma4(acc, r0, w0); edge_fma4(acc, r1, w1);
                wsum += w0 + w1;
            }
        }
        acc.x += __shfl_xor(acc.x, 32);
        acc.y += __shfl_xor(acc.y, 32);
        acc.z += __shfl_xor(acc.z, 32);
        acc.w += __shfl_xor(acc.w, 32);
        wsum  += __shfl_xor(wsum, 32);
        if (half == 0) {
            float inv = 1.0f / (wsum + EPS);
            *(float4*)&HN[nn][l32 * 4] =
                make_float4(acc.x * inv, acc.y * inv, acc.z * inv, acc.w * inv);
        }
    }
    __syncthreads();

    // GEMM: out[v][j] = sum_k x[v][k]*WT[k][j] + sum_k hn[v][k]*WT[128+k][j] + biases
    int j0 = (tid & 31) * 4;
    int ns = tid >> 5;
    float acc[4][4];
    #pragma unroll
    for (int n = 0; n < 4; ++n)
        #pragma unroll
        for (int j = 0; j < 4; ++j) acc[n][j] = 0.f;

    int rowc[4];
    #pragma unroll
    for (int n = 0; n < 4; ++n) {
        int rv = v0 + ns * 4 + n;
        rowc[n] = (rv < NN) ? rv : (NN - 1);   // clamped read; store is guarded
    }

    // self half: A from global x (per-wave broadcast, L1/L2-resident)
    for (int k4 = 0; k4 < 128; k4 += 4) {
        float4 w0 = *(const float4*)(WT + (k4 + 0) * D + j0);
        float4 w1 = *(const float4*)(WT + (k4 + 1) * D + j0);
        float4 w2 = *(const float4*)(WT + (k4 + 2) * D + j0);
        float4 w3 = *(const float4*)(WT + (k4 + 3) * D + j0);
        #pragma unroll
        for (int n = 0; n < 4; ++n) {
            float4 a = *(const float4*)(x + (size_t)rowc[n] * D + k4);
            acc[n][0] = fmaf(a.x, w0.x, fmaf(a.y, w1.x, fmaf(a.z, w2.x, fmaf(a.w, w3.x, acc[n][0]))));
            acc[n][1] = fmaf(a.x, w0.y, fmaf(a.y, w1.y, fmaf(a.z, w2.y, fmaf(a.w, w3.y, acc[n][1]))));
            acc[n][2] = fmaf(a.x, w0.z, fmaf(a.y, w1.z, fmaf(a.z, w2.z, fmaf(a.w, w3.z, acc[n][2]))));
            acc[n][3] = fmaf(a.x, w0.w, fmaf(a.y, w1.w, fmaf(a.z, w2.w, fmaf(a.w, w3.w, acc[n][3]))));
        }
    }
    // neigh half: A from LDS HN
    for (int k4 = 0; k4 < 128; k4 += 4) {
        float4 w0 = *(const float4*)(WT + (128 + k4 + 0) * D + j0);
        float4 w1 = *(const float4*)(WT + (128 + k4 + 1) * D + j0);
        float4 w2 = *(const float4*)(WT + (128 + k4 + 2) * D + j0);
        float4 w3 = *(const float4*)(WT + (128 + k4 + 3) * D + j0);
        #pragma unroll
        for (int n = 0; n < 4; ++n) {
            float4 a = *(const float4*)&HN[ns * 4 + n][k4];
            acc[n][0] = fmaf(a.x, w0.x, fmaf(a.y, w1.x, fmaf(a.z, w2.x, fmaf(a.w, w3.x, acc[n][0]))));
            acc[n][1] = fmaf(a.x, w0.y, fmaf(a.y, w1.y, fmaf(a.z, w2.y, fmaf(a.w, w3.y, acc[n][1]))));
            acc[n][2] = fmaf(a.x, w0.z, fmaf(a.y, w1.z, fmaf(a.z, w2.z, fmaf(a.w, w3.z, acc[n][2]))));
            acc[n][3] = fmaf(a.x, w0.w, fmaf(a.y, w1.w, fmaf(a.z, w2.w, fmaf(a.w, w3.w, acc[n][3]))));
        }
    }

    float4 b  = *(const float4*)(b_self + j0);
    float4 bp = *(const float4*)(bias + j0);
    b.x += bp.x; b.y += bp.y; b.z += bp.z; b.w += bp.w;

    #pragma unroll
    for (int n = 0; n < 4; ++n) {
        int v = v0 + ns * 4 + n;
        if (v < NN) {
            float4 o;
            o.x = acc[n][0] + b.x;
            o.y = acc[n][1] + b.y;
            o.z = acc[n][2] + b.z;
            o.w = acc[n][3] + b.w;
            *(float4*)(out + (size_t)v * D + j0) = o;
        }
    }
}

extern "C" void kernel_launch(void* const* d_in, const int* in_sizes, int n_in,
                              void* d_out, int out_size, void* d_ws, size_t ws_size,
                              hipStream_t stream) {
    const float* x   = (const float*)d_in[0];
    const int*   src = (const int*)d_in[1];
    const int*   dst = (const int*)d_in[2];
    const float* ew  = (const float*)d_in[3];
    const float* Ws  = (const float*)d_in[4];
    const float* bs  = (const float*)d_in[5];
    const float* Wn  = (const float*)d_in[6];
    const float* bp  = (const float*)d_in[7];
    float* out = (float*)d_out;

    int E = in_sizes[1];
    int EPAD = E + NSCAN;                       // room for 1 pad edge per node

    // workspace layout (4B units): count and edge_sw contiguous for single memset
    int*  wsi     = (int*)d_ws;
    int*  count   = wsi;                        // NSCAN
    int2* edge_sw = (int2*)(wsi + NSCAN);       // EPAD int2 (16B-aligned: NSCAN*4 % 16 == 0)
    int*  offsets = wsi + NSCAN + 2 * EPAD;     // NSCAN
    int*  cursor  = offsets + NSCAN;            // NSCAN
    int*  bsum    = cursor + NSCAN;             // 64
    float* WT     = (float*)(bsum + 64);        // 256*128 floats
    ushort* xb    = (ushort*)(WT + 256 * 128);  // NN*D bf16

    // zero count + edge_sw (pads must read as src=0, w=0)
    hipMemsetAsync(count, 0, (size_t)(NSCAN + 2 * EPAD) * sizeof(int), stream);

    int ncvt = NN * D / 4;
    int nmax = (E > ncvt) ? E : ncvt;
    prep_kernel<<<(nmax + 255) / 256, 256, 0, stream>>>(dst, count, x, xb, Ws, Wn, WT, E);

    scan1_kernel<<<NB_SCAN, 1024, 0, stream>>>(count, offsets, bsum);
    scan23_kernel<<<NB_SCAN, 1024, 0, stream>>>(offsets, bsum, cursor);
    csr_scatter_kernel<<<(E + 255) / 256, 256, 0, stream>>>(src, dst, ew, cursor, edge_sw, E);

    fused_out_kernel<<<(NN + 31) / 32, 256, 0, stream>>>(x, xb, offsets, edge_sw,
                                                         WT, bs, bp, out);
}